// Round 5
// baseline (173.706 us; speedup 1.0000x reference)
//
#include <hip/hip_runtime.h>

// Problem constants (from reference): B=16, L=512, D=512, T=4096, P=4
constexpr int Bn = 16;
constexpr int Ln = 512;
constexpr int Dn = 512;
constexpr int Tn = 4096;
constexpr int Pn = 4;

constexpr int ROW_F4 = (Dn + Pn) / 4;          // 129 float4 per output row
constexpr int TOTAL_F4 = Bn * Tn * ROW_F4;     // 8,454,144 float4 total
constexpr int NBLK = TOTAL_F4 / 256;           // 33,024 blocks
constexpr int NXCD = 8;
constexpr int BLK_PER_XCD = NBLK / NXCD;       // 4,128 = exactly 2 batches

// Native clang vector type: __builtin_nontemporal_* requires scalar/native
// vector, not HIP_vector_type<float,4>. Same 16-B layout as float4.
typedef float f4nt __attribute__((ext_vector_type(4)));

// Kernel 1: per-batch inclusive cumsum (LDS Hillis-Steele scan) + per-frame
// binary search (searchsorted side="right"). 4 blocks per batch; every
// idx_map entry written exactly once, coalesced — no init pass, no serial
// scatter loop. Frames >= cum[L-1] get -1 (output zeros for the D part).
__global__ __launch_bounds__(Ln) void cum_search_kernel(
    const int* __restrict__ durations, int* __restrict__ idx_map) {
    const int b     = blockIdx.x >> 2;   // batch
    const int chunk = blockIdx.x & 3;    // which 1024-frame chunk
    const int l     = threadIdx.x;       // 0..511

    __shared__ int cum[Ln];
    cum[l] = durations[b * Ln + l];
    __syncthreads();
    // Hillis-Steele inclusive scan
    for (int off = 1; off < Ln; off <<= 1) {
        int v = (l >= off) ? cum[l - off] : 0;
        __syncthreads();
        cum[l] += v;
        __syncthreads();
    }
    const int total = cum[Ln - 1];

    // 2 frames per thread, coalesced writes
    #pragma unroll
    for (int f = 0; f < 2; ++f) {
        const int t = chunk * 1024 + f * Ln + l;
        // first j with cum[j] > t  (== searchsorted(cum, t, side="right"))
        int lo = 0, hi = Ln;
        while (lo < hi) {
            const int mid = (lo + hi) >> 1;
            if (cum[mid] <= t) lo = mid + 1; else hi = mid;
        }
        const int idx = (t < total) ? min(lo, Ln - 1) : -1;
        idx_map[b * Tn + t] = idx;
    }
}

// Kernel 2: flattened streaming expand with XCD-aware swizzle + nontemporal
// output stores (135 MB write-once stream should not occupy L2; enc and
// idx_map stay resident). Blocks dispatch round-robin across 8 XCDs; the
// remap gives each XCD a contiguous 2-batch region (2 MB enc working set
// fits its private 4 MiB L2).
__global__ __launch_bounds__(256) void expand_flat_kernel(
    const f4nt* __restrict__ enc4, const f4nt* __restrict__ fpos4,
    const int* __restrict__ idx_map, f4nt* __restrict__ out4) {
    const int xcd = blockIdx.x & (NXCD - 1);
    const int j   = blockIdx.x >> 3;
    const int g   = (xcd * BLK_PER_XCD + j) * 256 + threadIdx.x;

    const int row = g / ROW_F4;                     // b*Tn + t
    const int c4  = g - row * ROW_F4;               // 0..128
    const int b   = row >> 12;                      // Tn = 4096 = 2^12

    f4nt v = (f4nt)(0.f);
    if (c4 == ROW_F4 - 1) {
        v = __builtin_nontemporal_load(&fpos4[row]);  // read-once stream
    } else {
        const int idx = idx_map[row];
        if (idx >= 0) {
            // enc float4 index: (b*Ln + idx) * (Dn/4) + c4  (cached: reused)
            v = enc4[(size_t)((b << 9) + idx) * (Dn / 4) + c4];
        }
    }
    __builtin_nontemporal_store(v, &out4[g]);       // write-once stream
}

extern "C" void kernel_launch(void* const* d_in, const int* in_sizes, int n_in,
                              void* d_out, int out_size, void* d_ws, size_t ws_size,
                              hipStream_t stream) {
    const float* enc  = (const float*)d_in[0];  // [B, L, D] f32
    const int*   dur  = (const int*)d_in[1];    // [B, L] i32
    const float* fpos = (const float*)d_in[2];  // [B, T, P] f32
    // d_in[3] = input_lengths, unused by the reference computation

    float* out = (float*)d_out;                 // [B, T, D+P] f32
    int* idx_map = (int*)d_ws;                  // [B, T] i32 = 256 KB scratch

    cum_search_kernel<<<Bn * 4, Ln, 0, stream>>>(dur, idx_map);

    static_assert(NBLK % NXCD == 0, "swizzle sizing");
    expand_flat_kernel<<<NBLK, 256, 0, stream>>>(
        (const f4nt*)enc, (const f4nt*)fpos, idx_map, (f4nt*)out);
}

// Round 6
// 161.329 us; speedup vs baseline: 1.0767x; 1.0767x over previous
//
#include <hip/hip_runtime.h>

// Problem constants (from reference): B=16, L=512, D=512, T=4096, P=4
constexpr int Bn = 16;
constexpr int Ln = 512;
constexpr int Dn = 512;
constexpr int Tn = 4096;
constexpr int Pn = 4;

constexpr int ROW_F4 = (Dn + Pn) / 4;          // 129 float4 per output row
constexpr int TOTAL_F4 = Bn * Tn * ROW_F4;     // 8,454,144 float4 total
constexpr int F4_PER_BLK = 512;                // 256 threads x 2 float4
constexpr int NBLK = TOTAL_F4 / F4_PER_BLK;    // 16,512 blocks
constexpr int NXCD = 8;
constexpr int BLK_PER_XCD = NBLK / NXCD;       // 2,064 = exactly 2 batches

// Kernel 1: per-batch inclusive cumsum (LDS Hillis-Steele scan) + per-frame
// binary search (searchsorted side="right"). 4 blocks per batch; every
// idx_map entry written exactly once, coalesced — no init pass, no serial
// scatter loop. Frames >= cum[L-1] get -1 (output zeros for the D part).
__global__ __launch_bounds__(Ln) void cum_search_kernel(
    const int* __restrict__ durations, int* __restrict__ idx_map) {
    const int b     = blockIdx.x >> 2;   // batch
    const int chunk = blockIdx.x & 3;    // which 1024-frame chunk
    const int l     = threadIdx.x;       // 0..511

    __shared__ int cum[Ln];
    cum[l] = durations[b * Ln + l];
    __syncthreads();
    // Hillis-Steele inclusive scan
    for (int off = 1; off < Ln; off <<= 1) {
        int v = (l >= off) ? cum[l - off] : 0;
        __syncthreads();
        cum[l] += v;
        __syncthreads();
    }
    const int total = cum[Ln - 1];

    // 2 frames per thread, coalesced writes
    #pragma unroll
    for (int f = 0; f < 2; ++f) {
        const int t = chunk * 1024 + f * Ln + l;
        // first j with cum[j] > t  (== searchsorted(cum, t, side="right"))
        int lo = 0, hi = Ln;
        while (lo < hi) {
            const int mid = (lo + hi) >> 1;
            if (cum[mid] <= t) lo = mid + 1; else hi = mid;
        }
        const int idx = (t < total) ? min(lo, Ln - 1) : -1;
        idx_map[b * Tn + t] = idx;
    }
}

// Kernel 2: flattened streaming expand, XCD-aware swizzle, 2 float4/thread.
// Regular (cached) stores — L2 write-coalescing; nt stores regressed in R5.
// Each block covers 512 consecutive float4; thread t stores base+t and
// base+256+t, so both halves are dense, line-aligned wave stores.
__global__ __launch_bounds__(256) void expand_flat_kernel(
    const float4* __restrict__ enc4, const float4* __restrict__ fpos4,
    const int* __restrict__ idx_map, float4* __restrict__ out4) {
    const int xcd = blockIdx.x & (NXCD - 1);
    const int j   = blockIdx.x >> 3;
    const int base = (xcd * BLK_PER_XCD + j) * F4_PER_BLK + threadIdx.x;

    #pragma unroll
    for (int h = 0; h < 2; ++h) {
        const int g   = base + h * 256;
        const int row = g / ROW_F4;                 // b*Tn + t
        const int c4  = g - row * ROW_F4;           // 0..128
        const int b   = row >> 12;                  // Tn = 4096 = 2^12

        float4 v = make_float4(0.f, 0.f, 0.f, 0.f);
        if (c4 == ROW_F4 - 1) {
            v = fpos4[row];
        } else {
            const int idx = idx_map[row];
            if (idx >= 0) {
                // enc float4 index: (b*Ln + idx) * (Dn/4) + c4
                v = enc4[(size_t)((b << 9) + idx) * (Dn / 4) + c4];
            }
        }
        out4[g] = v;
    }
}

extern "C" void kernel_launch(void* const* d_in, const int* in_sizes, int n_in,
                              void* d_out, int out_size, void* d_ws, size_t ws_size,
                              hipStream_t stream) {
    const float* enc  = (const float*)d_in[0];  // [B, L, D] f32
    const int*   dur  = (const int*)d_in[1];    // [B, L] i32
    const float* fpos = (const float*)d_in[2];  // [B, T, P] f32
    // d_in[3] = input_lengths, unused by the reference computation

    float* out = (float*)d_out;                 // [B, T, D+P] f32
    int* idx_map = (int*)d_ws;                  // [B, T] i32 = 256 KB scratch

    cum_search_kernel<<<Bn * 4, Ln, 0, stream>>>(dur, idx_map);

    static_assert(TOTAL_F4 % F4_PER_BLK == 0 && NBLK % NXCD == 0, "sizing");
    expand_flat_kernel<<<NBLK, 256, 0, stream>>>(
        (const float4*)enc, (const float4*)fpos, idx_map, (float4*)out);
}